// Round 5
// baseline (194.377 us; speedup 1.0000x reference)
//
#include <hip/hip_runtime.h>

#define NN   6
#define H1   64
#define H2   512
#define H3   256
#define TM   256          // batch rows per block
#define KC   32           // K-chunk (2 MFMA K-steps of 16)
#define NCH  (H2 / KC)    // 16 chunks
#define CHUNK_BYTES 32768 // KC*H3*2(bf16)*2(hi,lo)

typedef short s16x8 __attribute__((ext_vector_type(8)));
typedef float f32x16 __attribute__((ext_vector_type(16)));
typedef float f32x2 __attribute__((ext_vector_type(2)));
typedef unsigned int u32x4 __attribute__((ext_vector_type(4)));

__device__ __forceinline__ unsigned short f2bf(float x) {
    unsigned int u = __float_as_uint(x);
    u += 0x7FFFu + ((u >> 16) & 1u);          // round-to-nearest-even
    return (unsigned short)(u >> 16);
}
__device__ __forceinline__ float bf2f(unsigned short b) {
    return __uint_as_float(((unsigned int)b) << 16);
}
// packed f32x2 -> 2x bf16 in one u32 (lo short = first operand), RTNE
__device__ __forceinline__ unsigned int cvt_pk_bf16(float a, float b) {
    unsigned int r;
    asm("v_cvt_pk_bf16_f32 %0, %1, %2" : "=v"(r) : "v"(a), "v"(b));
    return r;
}
__device__ __forceinline__ void g2lds16(const void* g, void* l) {
    __builtin_amdgcn_global_load_lds(
        (const __attribute__((address_space(1))) unsigned int*)g,
        (__attribute__((address_space(3))) unsigned int*)l, 16, 0, 0);
}

// ---------------- kernel 1: split Wl2 into hi/lo bf16, fragment-ordered ----
// Output layout per chunk c0: hi block [th][col][j] (8192 shorts), then lo.
// (c0,p,th,col,j) = split_p( Wl2[k][col] ), k = c0*32 + th*8 + j.
// Reads coalesced: adjacent lanes read adjacent float4 along col.
__global__ void split_w(const float* __restrict__ Wl2,
                        unsigned short* __restrict__ Whl) {
    const int gid = blockIdx.x * 256 + threadIdx.x;   // [0, 32768)
    const int k = gid >> 6, c4 = (gid & 63) << 2;
    const float4 v = *(const float4*)&Wl2[k * H3 + c4];
    const int c0 = k >> 5, th = (k >> 3) & 3, j = k & 7;
    const unsigned base = (c0 << 14) + (th << 11) + j;
    const float vv[4] = {v.x, v.y, v.z, v.w};
    #pragma unroll
    for (int c = 0; c < 4; ++c) {
        const unsigned short hi = f2bf(vv[c]);
        const unsigned short lo = f2bf(vv[c] - bf2f(hi));
        Whl[base + ((c4 + c) << 3)] = hi;
        Whl[base + 8192 + ((c4 + c) << 3)] = lo;
    }
}

// --- generate A frags for TWO row-subtiles sharing one weight-load pass ---
__device__ __forceinline__ void gen2(const float* sBl0s, const float (*sWl0s)[H2],
                                     int k0, const float* xr0, const float* xr1,
                                     s16x8& ah0, s16x8& al0, s16x8& ah1, s16x8& al1)
{
    f32x2 a0[4], a1[4];
    #pragma unroll
    for (int j = 0; j < 4; ++j) {
        const f32x2 b = *(const f32x2*)&sBl0s[k0 + 2 * j];
        f32x2 c0 = b, c1 = b;
        #pragma unroll
        for (int i = 0; i < 6; ++i) {
            const f32x2 wv = *(const f32x2*)&sWl0s[i][k0 + 2 * j];
            c0 += xr0[i] * wv;
            c1 += xr1[i] * wv;
        }
        a0[j] = c0; a1[j] = c1;
    }
    unsigned int h0[4], l0[4], h1[4], l1[4];
    #pragma unroll
    for (int j = 0; j < 4; ++j) {
        f32x2 v = a0[j];
        v = __builtin_elementwise_max(v, 0.01f * v);
        unsigned int u = cvt_pk_bf16(v[0], v[1]);
        f32x2 hf = { __uint_as_float(u << 16), __uint_as_float(u & 0xFFFF0000u) };
        f32x2 r = v - hf;
        h0[j] = u; l0[j] = cvt_pk_bf16(r[0], r[1]);
        v = a1[j];
        v = __builtin_elementwise_max(v, 0.01f * v);
        u = cvt_pk_bf16(v[0], v[1]);
        hf = (f32x2){ __uint_as_float(u << 16), __uint_as_float(u & 0xFFFF0000u) };
        r = v - hf;
        h1[j] = u; l1[j] = cvt_pk_bf16(r[0], r[1]);
    }
    u32x4 t;
    t = (u32x4){h0[0], h0[1], h0[2], h0[3]}; ah0 = __builtin_bit_cast(s16x8, t);
    t = (u32x4){l0[0], l0[1], l0[2], l0[3]}; al0 = __builtin_bit_cast(s16x8, t);
    t = (u32x4){h1[0], h1[1], h1[2], h1[3]}; ah1 = __builtin_bit_cast(s16x8, t);
    t = (u32x4){l1[0], l1[1], l1[2], l1[3]}; al1 = __builtin_bit_cast(s16x8, t);
}

// ---------------- kernel 2: fused graph-conv + MLP with split-bf16 MFMA ----
// 8 waves = 4 row-groups x 2 col-groups; wave = 64 rows x 128 cols.
__global__ __launch_bounds__(512, 2)
void gcn_mfma(const float* __restrict__ f,    // [6][B]
              const float* __restrict__ W0,   // [64]
              const float* __restrict__ b0,   // [64]
              const float* __restrict__ W1,   // [64]
              const float* __restrict__ b1_,  // [1]
              const float* __restrict__ Wl0,  // [6][512]
              const float* __restrict__ bl0,  // [512]
              const float* __restrict__ bl2,  // [256]
              const float* __restrict__ Wl3,  // [256]
              const float* __restrict__ bl3_, // [1]
              const unsigned short* __restrict__ Whl, // pre-split Wl2
              float* __restrict__ out,        // [B]
              int B)
{
    __shared__ float sW0[H1], sB0[H1], sW1[H1];
    __shared__ float sWl0[NN][H2];
    __shared__ float sBl0[H2];
    __shared__ float sBl2[H3];
    __shared__ float sWl3[H3];
    __shared__ float sF[NN][TM];
    __shared__ float sS[NN][TM];
    __shared__ float sX[NN][TM];
    __shared__ __align__(16) unsigned short sB[2][16384]; // 2 x 32 KiB W chunks

    const int t     = threadIdx.x;
    const int lane  = t & 63;
    const int w     = t >> 6;        // wave 0..7
    const int cl    = lane & 31;     // row (A) / col (B) within tile
    const int h     = lane >> 5;     // k-octet selector
    const int wr    = w >> 1;        // row-group 0..3 (64 rows each)
    const int wc    = w & 1;         // col-group 0..1 (128 cols each)
    const int wc128 = wc << 7;
    const int m0    = blockIdx.x * TM;

    // ---- stage small weights + input tile ----
    for (int i = t; i < H1; i += 512) { sW0[i] = W0[i]; sB0[i] = b0[i]; sW1[i] = W1[i]; }
    for (int i = t; i < NN * H2; i += 512) sWl0[i >> 9][i & (H2 - 1)] = Wl0[i];
    for (int i = t; i < H2; i += 512) sBl0[i] = bl0[i];
    for (int i = t; i < H3; i += 512) { sBl2[i] = bl2[i]; sWl3[i] = Wl3[i]; }
    for (int i = t; i < NN * TM; i += 512) sF[i >> 8][i & 255] = f[(i >> 8) * B + m0 + (i & 255)];

#define STAGE(CH, BUF) do {                                                        \
        const char* _src = (const char*)Whl + (CH) * CHUNK_BYTES + (w << 12) + (lane << 4); \
        char*       _dst = (char*)&sB[BUF][0] + (w << 12);                         \
        _Pragma("unroll")                                                          \
        for (int _q = 0; _q < 4; ++_q) g2lds16(_src + (_q << 10), _dst + (_q << 10)); \
    } while (0)

    STAGE(0, 0);
    __syncthreads();

    const float b1v = b1_[0];

    // ---- graph convs collapsed to scalar recurrences (ring, deg=2) ----
    for (int v = t; v < NN * TM; v += 512) {
        const int i = v >> 8, r = v & 255;
        const int im = (i + NN - 1) % NN, ip = (i + 1) % NN;
        const float g = 0.5f * (sF[im][r] + sF[ip][r]);
        float s = 0.f;
        #pragma unroll
        for (int c = 0; c < H1; ++c) {
            float hx = g * sW0[c] + sB0[c];
            hx = fmaxf(hx, 0.01f * hx);
            s += hx * sW1[c];
        }
        sS[i][r] = s;
    }
    __syncthreads();
    for (int v = t; v < NN * TM; v += 512) {
        const int i = v >> 8, r = v & 255;
        const int im = (i + NN - 1) % NN, ip = (i + 1) % NN;
        const float xv = 0.5f * (sS[im][r] + sS[ip][r]) + b1v;
        sX[i][r] = fmaxf(xv, 0.01f * xv);
    }
    __syncthreads();

    // per-lane x rows for the two row-subtiles
    const int row0 = (wr << 6) + cl;
    float xr0[NN], xr1[NN];
    #pragma unroll
    for (int i = 0; i < NN; ++i) { xr0[i] = sX[i][row0]; xr1[i] = sX[i][row0 + 32]; }

    f32x16 acc[2][4];
    #pragma unroll
    for (int m = 0; m < 2; ++m)
        #pragma unroll
        for (int n = 0; n < 4; ++n)
            #pragma unroll
            for (int rg = 0; rg < 16; ++rg) acc[m][n][rg] = 0.f;

#define K0(CH, TT) (((CH) << 5) + ((TT) << 4) + (h << 3))

    // --- MFMA for one k-step: 4 col-tiles x {Ah*Bh, Al*Bh, Ah*Bl} x 2 row-tiles
#define MFMA_TT(SBC, TT, AH0, AL0, AH1, AL1) do {                                  \
        const int _thh = ((TT) << 1) + h;                                          \
        const unsigned short* _bb = &(SBC)[((_thh << 8) + wc128 + cl) << 3];       \
        s16x8 _bh[4], _bl[4];                                                      \
        _Pragma("unroll")                                                          \
        for (int _n = 0; _n < 4; ++_n) {                                           \
            _bh[_n] = *(const s16x8*)&_bb[_n << 8];                                \
            _bl[_n] = *(const s16x8*)&_bb[8192 + (_n << 8)];                       \
        }                                                                          \
        _Pragma("unroll")                                                          \
        for (int _n = 0; _n < 4; ++_n) {                                           \
            acc[0][_n] = __builtin_amdgcn_mfma_f32_32x32x16_bf16(AH0, _bh[_n], acc[0][_n], 0, 0, 0); \
            acc[1][_n] = __builtin_amdgcn_mfma_f32_32x32x16_bf16(AH1, _bh[_n], acc[1][_n], 0, 0, 0); \
            acc[0][_n] = __builtin_amdgcn_mfma_f32_32x32x16_bf16(AL0, _bh[_n], acc[0][_n], 0, 0, 0); \
            acc[1][_n] = __builtin_amdgcn_mfma_f32_32x32x16_bf16(AL1, _bh[_n], acc[1][_n], 0, 0, 0); \
            acc[0][_n] = __builtin_amdgcn_mfma_f32_32x32x16_bf16(AH0, _bl[_n], acc[0][_n], 0, 0, 0); \
            acc[1][_n] = __builtin_amdgcn_mfma_f32_32x32x16_bf16(AH1, _bl[_n], acc[1][_n], 0, 0, 0); \
        }                                                                          \
    } while (0)

    s16x8 fA[2][4], fB[2][4];   // [TT][ah0,al0,ah1,al1] for even/odd chunks
    gen2(sBl0, sWl0, K0(0, 0), xr0, xr1, fA[0][0], fA[0][1], fA[0][2], fA[0][3]);
    gen2(sBl0, sWl0, K0(0, 1), xr0, xr1, fA[1][0], fA[1][1], fA[1][2], fA[1][3]);

    // ---- main loop, hand-unrolled by 2 (static buffer selection) ----
    for (int ch = 0; ch < NCH; ch += 2) {
        STAGE(ch + 1, 1);
        gen2(sBl0, sWl0, K0(ch + 1, 0), xr0, xr1, fB[0][0], fB[0][1], fB[0][2], fB[0][3]);
        gen2(sBl0, sWl0, K0(ch + 1, 1), xr0, xr1, fB[1][0], fB[1][1], fB[1][2], fB[1][3]);
        MFMA_TT((&sB[0][0]), 0, fA[0][0], fA[0][1], fA[0][2], fA[0][3]);
        MFMA_TT((&sB[0][0]), 1, fA[1][0], fA[1][1], fA[1][2], fA[1][3]);
        __syncthreads();
        if (ch + 2 < NCH) {
            STAGE(ch + 2, 0);
            gen2(sBl0, sWl0, K0(ch + 2, 0), xr0, xr1, fA[0][0], fA[0][1], fA[0][2], fA[0][3]);
            gen2(sBl0, sWl0, K0(ch + 2, 1), xr0, xr1, fA[1][0], fA[1][1], fA[1][2], fA[1][3]);
        }
        MFMA_TT((&sB[1][0]), 0, fB[0][0], fB[0][1], fB[0][2], fB[0][3]);
        MFMA_TT((&sB[1][0]), 1, fB[1][0], fB[1][1], fB[1][2], fB[1][3]);
        __syncthreads();
    }

    // ---- epilogue: bl2 + lrelu, dot with Wl3 (per col-group), reduce ----
    float ps[2][16];
    #pragma unroll
    for (int m = 0; m < 2; ++m)
        #pragma unroll
        for (int rg = 0; rg < 16; ++rg) ps[m][rg] = 0.f;
    #pragma unroll
    for (int m = 0; m < 2; ++m)
        #pragma unroll
        for (int n = 0; n < 4; ++n) {
            const int col = wc128 + (n << 5) + cl;
            const float b2 = sBl2[col], w3 = sWl3[col];
            #pragma unroll
            for (int rg = 0; rg < 16; ++rg) {
                float v = acc[m][n][rg] + b2;
                v = fmaxf(v, 0.01f * v);
                ps[m][rg] += v * w3;
            }
        }
    #pragma unroll
    for (int msk = 1; msk < 32; msk <<= 1)
        #pragma unroll
        for (int m = 0; m < 2; ++m)
            #pragma unroll
            for (int rg = 0; rg < 16; ++rg) ps[m][rg] += __shfl_xor(ps[m][rg], msk);

    float* sRed = &sS[0][0];     // reuse sS: [2][256] partials
    if (cl == 0) {
        #pragma unroll
        for (int m = 0; m < 2; ++m)
            #pragma unroll
            for (int rg = 0; rg < 16; ++rg) {
                const int rowb = (wr << 6) + (m << 5) + (rg & 3) + ((rg >> 2) << 3) + (h << 2);
                sRed[(wc << 8) + rowb] = ps[m][rg];
            }
    }
    __syncthreads();
    if (t < 256) {
        const float bl3v = bl3_[0];
        const float v = sRed[t] + sRed[256 + t] + bl3v;
        out[m0 + t] = fmaxf(v, 0.01f * v);
    }
}

extern "C" void kernel_launch(void* const* d_in, const int* in_sizes, int n_in,
                              void* d_out, int out_size, void* d_ws, size_t ws_size,
                              hipStream_t stream) {
    const float* f   = (const float*)d_in[0];
    const float* W0  = (const float*)d_in[3];
    const float* b0  = (const float*)d_in[4];
    const float* W1  = (const float*)d_in[5];
    const float* b1  = (const float*)d_in[6];
    const float* Wl0 = (const float*)d_in[7];
    const float* bl0 = (const float*)d_in[8];
    const float* Wl2 = (const float*)d_in[9];
    const float* bl2 = (const float*)d_in[10];
    const float* Wl3 = (const float*)d_in[11];
    const float* bl3 = (const float*)d_in[12];
    float* out = (float*)d_out;
    unsigned short* Whl = (unsigned short*)d_ws;   // 512 KiB
    const int B = in_sizes[0] / NN;

    split_w<<<dim3(128), 256, 0, stream>>>(Wl2, Whl);
    gcn_mfma<<<dim3(B / TM), 512, 0, stream>>>(f, W0, b0, W1, b1, Wl0, bl0,
                                               bl2, Wl3, bl3, Whl, out, B);
}